// Round 14
// baseline (155.332 us; speedup 1.0000x reference)
//
#include <hip/hip_runtime.h>

// ---------------------------------------------------------------------------
// QuaternionLinear == one dense GEMM: out[M,N] = x[M,K] @ W_eff[N,K]^T + bias
//   M = 16384 (B*S), N = 2048 (OUT_F), K = 2048 (IN_F)
// Pipeline: prep (fp32->bf16 x + build W_eff) ; qgemm.
// R14 = R13 (one-cluster operand lookahead, A 2-ring + B 3-ring 160KB,
// chunk-XOR swizzle, ONE end-of-tile lgkm(0)+vmcnt(4)+barrier, literal ring
// indices, XCD swizzle) + INSTRUCTION-GRANULARITY INTERLEAVE: the lookahead
// reads are spread INSIDE the MFMA bursts (1 ds_read per 2 MFMA) in source
// order. R13 proved lookahead works (+8us, MfmaUtil 50->54.6) but the wave
// still issued [8 reads][16 MFMA] as blocks -> in-order issue starves the
// LDS pipe during bursts and the MFMA pipe during read blocks (phase 1087
// cyc vs overlap floor ~704). Alternating issue feeds both pipes.
// Lessons kept: R12 (B prefetch distance), R11 (16x16 frags only),
// R9 (no divergence around acc), R6 (literal ring indices).
// ---------------------------------------------------------------------------

typedef unsigned short u16;
typedef __bf16 bf16x8 __attribute__((ext_vector_type(8)));
typedef float f32x4 __attribute__((ext_vector_type(4)));

#define QM 16384
#define QN 2048
#define QK 2048

__device__ __forceinline__ u16 f2bf(float f) {
    union { float f; unsigned u; } v;
    v.f = f;
    unsigned r = v.u + 0x7FFFu + ((v.u >> 16) & 1u);
    return (u16)(r >> 16);
}

__device__ __forceinline__ void async_copy16(const u16* g, u16* l) {
    __builtin_amdgcn_global_load_lds(
        (const __attribute__((address_space(1))) void*)g,
        (__attribute__((address_space(3))) void*)l,
        16, 0, 0);
}

// ---------------------------------------------------------------------------
// prep: blocks [0,4096) convert x fp32->bf16; blocks [4096,8192) build W_eff.
// ---------------------------------------------------------------------------
__global__ void prep_kernel(const float* __restrict__ x, u16* __restrict__ xb,
                            const float* __restrict__ wr, const float* __restrict__ wi,
                            const float* __restrict__ wj, const float* __restrict__ wk,
                            u16* __restrict__ wb) {
    const int b = blockIdx.x;
    if (b < 4096) {
        const int n4 = (QM * QK) / 4;
        for (int i = b * blockDim.x + threadIdx.x; i < n4; i += 4096 * blockDim.x) {
            float4 v = reinterpret_cast<const float4*>(x)[i];
            ushort4 o;
            o.x = f2bf(v.x); o.y = f2bf(v.y); o.z = f2bf(v.z); o.w = f2bf(v.w);
            reinterpret_cast<ushort4*>(xb)[i] = o;
        }
    } else {
        int i = (b - 4096) * blockDim.x + threadIdx.x;   // [0, QN*QK/4)
        int n = i >> 9;
        int p = i & 511;
        int q = n >> 2, co = n & 3;
        int base = (q << 9) + p;
        float r  = wr[base], ii = wi[base], jj = wj[base], kk = wk[base];
        float e0, e1, e2, e3;
        if      (co == 0) { e0 = r;  e1 = -ii; e2 = -jj; e3 = -kk; }
        else if (co == 1) { e0 = ii; e1 = r;   e2 = -jj; e3 = kk;  }
        else if (co == 2) { e0 = jj; e1 = ii;  e2 = r;   e3 = -kk; }
        else              { e0 = kk; e1 = -ii; e2 = jj;  e3 = r;   }
        ushort4 o;
        o.x = f2bf(e0); o.y = f2bf(e1); o.z = f2bf(e2); o.w = f2bf(e3);
        reinterpret_cast<ushort4*>(wb)[(n << 9) + p] = o;
    }
}

#define MFMA1(mi, ni, av, bv) \
    acc[mi][ni] = __builtin_amdgcn_mfma_f32_16x16x32_bf16(av, bv, acc[mi][ni], 0, 0, 0)

// ---------------------------------------------------------------------------
// LDS (u16): A bufs [0,32768) = 2 x 16384; B bufs [32768,81920) = 3 x 16384.
// Buf = 256 rows x 64 cols; physical 16B-chunk (r,cp) holds logical
// (r, cp ^ (r&7)) [involution, verified 0-conflict 16x16 read pattern].
// Race proof identical to R13 ([1]-[4] in that round's header).
// ---------------------------------------------------------------------------
__global__ __launch_bounds__(512, 2) void qgemm_kernel(const u16* __restrict__ A,
                                                       const u16* __restrict__ B,
                                                       const float* __restrict__ bias,
                                                       float* __restrict__ C) {
    __shared__ __align__(16) u16 L[81920];      // 160 KB

    const int bid = blockIdx.x;                 // 512 blocks, %8==0
    const int swz = (bid & 7) * 64 + (bid >> 3);
    const int bm = swz >> 3;                    // 0..63
    const int bn = swz & 7;                     // 0..7

    const int tid = threadIdx.x;
    const int wid = tid >> 6, lane = tid & 63;
    const int wm = wid >> 2, wn = wid & 3;
    const int lr = lane & 15, lg = lane >> 4;

    const u16* Asrc = A + (size_t)bm * 256 * QK;
    const u16* Bsrc = B + (size_t)bn * 256 * QK;

    const int rA  = tid >> 3;                        // 0..63
    const int clA = ((tid & 7) ^ (rA & 7)) << 3;     // pre-swizzled global col
    const size_t soff = (size_t)rA * QK + clA;

    f32x4 acc[8][4];
#pragma unroll
    for (int i = 0; i < 8; ++i)
#pragma unroll
        for (int j = 0; j < 4; ++j)
            acc[i][j] = (f32x4){0.f, 0.f, 0.f, 0.f};

    auto stage = [&](const u16* src, int lbase, int k0) {
#pragma unroll
        for (int o = 0; o < 2; ++o)
            async_copy16(src + (size_t)(o * 64) * QK + k0 + soff,
                         &L[lbase + o * 4096 + wid * 512]);
    };

    auto rdA = [&](const u16* LA, int mf, int ks) -> bf16x8 {
        const int r = wm * 128 + mf * 16 + lr;
        const int c = ((ks * 4 + lg) ^ (r & 7)) << 3;
        return *(const bf16x8*)&LA[r * 64 + c];
    };
    auto rdB = [&](const u16* LB, int nf, int ks) -> bf16x8 {
        const int r = wn * 64 + nf * 16 + lr;
        const int c = ((ks * 4 + lg) ^ (r & 7)) << 3;
        return *(const bf16x8*)&LB[r * 64 + c];
    };

    // carried across tiles: current tile's c0 operands
    bf16x8 a0[4], b0[4];

    // ab=t&1, bt=t%3, bt2=(t+2)%3, abn=(t+1)&1, btn=(t+1)%3 — all LITERAL.
    auto doTile = [&](const int ab, const int bt, const int bt2,
                      const int abn, const int btn, const int t,
                      const bool preRead) __attribute__((always_inline)) {
        const u16* LA  = &L[ab * 16384];
        const u16* LB  = &L[32768 + bt * 16384];
        const u16* LAn = &L[abn * 16384];
        const u16* LBn = &L[32768 + btn * 16384];
        const int tw1 = (t + 1) & 31, tw2 = (t + 2) & 31;
        const int oA = abn * 16384;               // A(t+1) dest
        const int oB = 32768 + bt2 * 16384;       // B(t+2) dest

        bf16x8 a1[4], b1[4], a2[4], a3[4];

        // ---- phase c0: MFMA rows0-3 (a0xb0), reads a1 interleaved --------
        stage(Asrc, oA, tw1 * 64);
        MFMA1(0, 0, a0[0], b0[0]); MFMA1(0, 1, a0[0], b0[1]);
        a1[0] = rdA(LA, 4, 0);
        MFMA1(0, 2, a0[0], b0[2]); MFMA1(0, 3, a0[0], b0[3]);
        a1[1] = rdA(LA, 5, 0);
        MFMA1(1, 0, a0[1], b0[0]); MFMA1(1, 1, a0[1], b0[1]);
        a1[2] = rdA(LA, 6, 0);
        MFMA1(1, 2, a0[1], b0[2]); MFMA1(1, 3, a0[1], b0[3]);
        a1[3] = rdA(LA, 7, 0);
        MFMA1(2, 0, a0[2], b0[0]); MFMA1(2, 1, a0[2], b0[1]);
        MFMA1(2, 2, a0[2], b0[2]); MFMA1(2, 3, a0[2], b0[3]);
        MFMA1(3, 0, a0[3], b0[0]); MFMA1(3, 1, a0[3], b0[1]);
        MFMA1(3, 2, a0[3], b0[2]); MFMA1(3, 3, a0[3], b0[3]);

        // ---- phase c1: MFMA rows4-7 (a1xb0), reads b1,a2 interleaved -----
        stage(Asrc + 128 * QK, oA + 8192, tw1 * 64);
        MFMA1(4, 0, a1[0], b0[0]); MFMA1(4, 1, a1[0], b0[1]);
        b1[0] = rdB(LB, 0, 1);
        MFMA1(4, 2, a1[0], b0[2]); MFMA1(4, 3, a1[0], b0[3]);
        b1[1] = rdB(LB, 1, 1);
        MFMA1(5, 0, a1[1], b0[0]); MFMA1(5, 1, a1[1], b0[1]);
        b1[2] = rdB(LB, 2, 1);
        MFMA1(5, 2, a1[1], b0[2]); MFMA1(5, 3, a1[1], b0[3]);
        b1[3] = rdB(LB, 3, 1);
        MFMA1(6, 0, a1[2], b0[0]); MFMA1(6, 1, a1[2], b0[1]);
        a2[0] = rdA(LA, 0, 1);
        MFMA1(6, 2, a1[2], b0[2]); MFMA1(6, 3, a1[2], b0[3]);
        a2[1] = rdA(LA, 1, 1);
        MFMA1(7, 0, a1[3], b0[0]); MFMA1(7, 1, a1[3], b0[1]);
        a2[2] = rdA(LA, 2, 1);
        MFMA1(7, 2, a1[3], b0[2]); MFMA1(7, 3, a1[3], b0[3]);
        a2[3] = rdA(LA, 3, 1);

        // ---- phase c2: MFMA rows0-3 (a2xb1), reads a3 interleaved --------
        stage(Bsrc, oB, tw2 * 64);
        MFMA1(0, 0, a2[0], b1[0]); MFMA1(0, 1, a2[0], b1[1]);
        a3[0] = rdA(LA, 4, 1);
        MFMA1(0, 2, a2[0], b1[2]); MFMA1(0, 3, a2[0], b1[3]);
        a3[1] = rdA(LA, 5, 1);
        MFMA1(1, 0, a2[1], b1[0]); MFMA1(1, 1, a2[1], b1[1]);
        a3[2] = rdA(LA, 6, 1);
        MFMA1(1, 2, a2[1], b1[2]); MFMA1(1, 3, a2[1], b1[3]);
        a3[3] = rdA(LA, 7, 1);
        MFMA1(2, 0, a2[2], b1[0]); MFMA1(2, 1, a2[2], b1[1]);
        MFMA1(2, 2, a2[2], b1[2]); MFMA1(2, 3, a2[2], b1[3]);
        MFMA1(3, 0, a2[3], b1[0]); MFMA1(3, 1, a2[3], b1[1]);
        MFMA1(3, 2, a2[3], b1[2]); MFMA1(3, 3, a2[3], b1[3]);

        // ---- phase c3: stage B h1; END sync; MFMA rows4-7 (a3xb1) with
        //      next tile's c0 reads interleaved after the barrier ----------
        stage(Bsrc + 128 * QK, oB + 8192, tw2 * 64);
        asm volatile("s_waitcnt lgkmcnt(0) vmcnt(4)" ::: "memory");
        __builtin_amdgcn_s_barrier();
        MFMA1(4, 0, a3[0], b1[0]); MFMA1(4, 1, a3[0], b1[1]);
        if (preRead) b0[0] = rdB(LBn, 0, 0);
        MFMA1(4, 2, a3[0], b1[2]); MFMA1(4, 3, a3[0], b1[3]);
        if (preRead) b0[1] = rdB(LBn, 1, 0);
        MFMA1(5, 0, a3[1], b1[0]); MFMA1(5, 1, a3[1], b1[1]);
        if (preRead) b0[2] = rdB(LBn, 2, 0);
        MFMA1(5, 2, a3[1], b1[2]); MFMA1(5, 3, a3[1], b1[3]);
        if (preRead) b0[3] = rdB(LBn, 3, 0);
        MFMA1(6, 0, a3[2], b1[0]); MFMA1(6, 1, a3[2], b1[1]);
        if (preRead) a0[0] = rdA(LAn, 0, 0);
        MFMA1(6, 2, a3[2], b1[2]); MFMA1(6, 3, a3[2], b1[3]);
        if (preRead) a0[1] = rdA(LAn, 1, 0);
        MFMA1(7, 0, a3[3], b1[0]); MFMA1(7, 1, a3[3], b1[1]);
        if (preRead) a0[2] = rdA(LAn, 2, 0);
        MFMA1(7, 2, a3[3], b1[2]); MFMA1(7, 3, a3[3], b1[3]);
        if (preRead) a0[3] = rdA(LAn, 3, 0);
    };

    // prologue: A(0)->Abuf0, B(0)->Bbuf0, B(1)->Bbuf1
    stage(Asrc,            0,             0);
    stage(Asrc + 128 * QK, 8192,          0);
    stage(Bsrc,            32768,             0);
    stage(Bsrc + 128 * QK, 32768 + 8192,      0);
    stage(Bsrc,            32768 + 16384,        64);
    stage(Bsrc + 128 * QK, 32768 + 16384 + 8192, 64);
    asm volatile("s_waitcnt vmcnt(4)" ::: "memory");   // A(0),B(0) resident
    __builtin_amdgcn_s_barrier();
#pragma unroll
    for (int nf = 0; nf < 4; ++nf) b0[nf] = rdB(&L[32768], nf, 0);
#pragma unroll
    for (int mf = 0; mf < 4; ++mf) a0[mf] = rdA(&L[0], mf, 0);

    // 32 tiles = 5 x 6 (lcm of rings 2,3) + 2 tail; literal ring indices.
    //            ab bt bt2 abn btn  t
    for (int t = 0; t < 30; t += 6) {
        doTile(0, 0, 2, 1, 1, t,     true);
        doTile(1, 1, 0, 0, 2, t + 1, true);
        doTile(0, 2, 1, 1, 0, t + 2, true);
        doTile(1, 0, 2, 0, 1, t + 3, true);
        doTile(0, 1, 0, 1, 2, t + 4, true);
        doTile(1, 2, 1, 0, 0, t + 5, true);
    }
    doTile(0, 0, 2, 1, 1, 30, true);
    doTile(1, 1, 0, 0, 2, 31, false);   // last tile: no wrap pre-read

    // epilogue: C/D layout col = lane&15, row = (lane>>4)*4 + reg
    const int colbase = bn * 256 + wn * 64;
    const int rowbase = bm * 256 + wm * 128;
    float bsv[4];
#pragma unroll
    for (int nf = 0; nf < 4; ++nf) bsv[nf] = bias[colbase + nf * 16 + lr];
    float* Cb = C + (size_t)rowbase * QN + colbase;
#pragma unroll
    for (int mf = 0; mf < 8; ++mf)
#pragma unroll
        for (int nf = 0; nf < 4; ++nf)
#pragma unroll
            for (int v = 0; v < 4; ++v)
                Cb[(size_t)(mf * 16 + lg * 4 + v) * QN + nf * 16 + lr] = acc[mf][nf][v] + bsv[nf];
}

// ---------------------------------------------------------------------------
extern "C" void kernel_launch(void* const* d_in, const int* in_sizes, int n_in,
                              void* d_out, int out_size, void* d_ws, size_t ws_size,
                              hipStream_t stream) {
    const float* x    = (const float*)d_in[0];
    const float* wr   = (const float*)d_in[1];
    const float* wi   = (const float*)d_in[2];
    const float* wj   = (const float*)d_in[3];
    const float* wk   = (const float*)d_in[4];
    const float* bias = (const float*)d_in[5];
    float* out = (float*)d_out;

    u16* xb = (u16*)d_ws;                                   // 64 MB
    u16* wb = (u16*)((char*)d_ws + (size_t)QM * QK * 2);    // 8 MB

    prep_kernel<<<8192, 256, 0, stream>>>(x, xb, wr, wi, wj, wk, wb);
    qgemm_kernel<<<512, 512, 0, stream>>>(xb, wb, bias, out);
}